// Round 2
// baseline (602.274 us; speedup 1.0000x reference)
//
#include <hip/hip_runtime.h>

#define N_NODES 50000
#define N_EDGES 800000

static __device__ __forceinline__ float lrelu(float x) { return fmaxf(x, 0.2f * x); }

// ---------------- CSR build ----------------
__global__ void k_count(const int* __restrict__ dst, int* __restrict__ deg) {
    int e = blockIdx.x * blockDim.x + threadIdx.x;
    if (e < N_EDGES) atomicAdd(&deg[dst[e]], 1);
}

__global__ void k_scan(const int* __restrict__ deg, int* __restrict__ rowp) {
    __shared__ int part[1024];
    const int T = 1024;
    const int C = (N_NODES + T - 1) / T;  // 49
    int t = threadIdx.x;
    int lo = t * C;
    int hi = min(lo + C, N_NODES);
    int s = 0;
    for (int i = lo; i < hi; ++i) s += deg[i];
    part[t] = s;
    __syncthreads();
    // inclusive Hillis-Steele scan
    for (int off = 1; off < T; off <<= 1) {
        int v = (t >= off) ? part[t - off] : 0;
        __syncthreads();
        part[t] += v;
        __syncthreads();
    }
    int base = (t == 0) ? 0 : part[t - 1];
    for (int i = lo; i < hi; ++i) { rowp[i] = base; base += deg[i]; }
    if (t == T - 1) rowp[N_NODES] = part[T - 1];
}

__global__ void k_scatter(const int* __restrict__ src, const int* __restrict__ dst,
                          const int* __restrict__ rowp, int* __restrict__ fill,
                          int* __restrict__ col) {
    int e = blockIdx.x * blockDim.x + threadIdx.x;
    if (e < N_EDGES) {
        int d = dst[e];
        int pos = rowp[d] + atomicAdd(&fill[d], 1);
        col[pos] = src[e];
    }
}

// ---------------- feat = x @ W, plus el/er reductions ----------------
// block = 192 threads (3 waves; wave w == head w), NPB nodes per block.
template <int K>
__global__ void k_feat(const float* __restrict__ x, const float* __restrict__ W,
                       const float* __restrict__ al, const float* __restrict__ ar,
                       float* __restrict__ feat, float* __restrict__ el, float* __restrict__ er) {
    __shared__ float Wl[K * 192];
    __shared__ float xl[K];
    const int NPB = 8;
    int c = threadIdx.x;  // 0..191 : output column = h*64+f
    int h = c >> 6;
    for (int k = 0; k < K; ++k) Wl[k * 192 + c] = W[k * 192 + c];
    float alc = al[c];
    float arc = ar[c];
    int n0 = blockIdx.x * NPB;
    for (int i = 0; i < NPB; ++i) {
        int n = n0 + i;
        if (n >= N_NODES) break;  // uniform across block
        __syncthreads();
        if (c < K) xl[c] = x[n * K + c];
        __syncthreads();
        float acc = 0.f;
#pragma unroll
        for (int k = 0; k < K; ++k) acc += xl[k] * Wl[k * 192 + c];
        feat[n * 192 + c] = acc;
        float e1 = acc * alc, e2 = acc * arc;
#pragma unroll
        for (int off = 32; off > 0; off >>= 1) {
            e1 += __shfl_down(e1, off);
            e2 += __shfl_down(e2, off);
        }
        if ((c & 63) == 0) {
            el[n * 3 + h] = e1;
            er[n * 3 + h] = e2;
        }
    }
}

// ---------------- aggregation: one wave per destination node (F=64) ----------------
__global__ void __launch_bounds__(256) k_agg(const float* __restrict__ feat,
                                             const float* __restrict__ el,
                                             const float* __restrict__ er,
                                             const float* __restrict__ bias,
                                             const int* __restrict__ rowp,
                                             const int* __restrict__ col,
                                             float* __restrict__ hout) {
    int wave = (blockIdx.x * blockDim.x + threadIdx.x) >> 6;
    int lane = threadIdx.x & 63;
    if (wave >= N_NODES) return;
    int n = wave;
    int jb = rowp[n], je = rowp[n + 1];
    float er0 = er[n * 3 + 0], er1 = er[n * 3 + 1], er2 = er[n * 3 + 2];
    float a0 = 0.f, a1 = 0.f, a2 = 0.f;
    float s0 = 0.f, s1 = 0.f, s2 = 0.f;
    for (int j = jb; j < je; ++j) {
        int s = col[j];
        float w0 = __expf(lrelu(el[s * 3 + 0] + er0));
        float w1 = __expf(lrelu(el[s * 3 + 1] + er1));
        float w2 = __expf(lrelu(el[s * 3 + 2] + er2));
        const float* fs = feat + (long)s * 192;
        a0 += w0 * fs[lane];
        a1 += w1 * fs[64 + lane];
        a2 += w2 * fs[128 + lane];
        s0 += w0; s1 += w1; s2 += w2;
    }
    float r = 0.f;
    if (je > jb) r = a0 / s0 + a1 / s1 + a2 / s2;
    r += bias[lane] + bias[64 + lane] + bias[128 + lane];
    hout[n * 64 + lane] = r;
}

// ---------------- layer 3: feat3 = h @ W3 (64->6), el3/er3 ----------------
__global__ void k_feat3(const float* __restrict__ x, const float* __restrict__ W3,
                        const float* __restrict__ al3, const float* __restrict__ ar3,
                        float* __restrict__ feat3, float* __restrict__ el3, float* __restrict__ er3) {
    __shared__ float Wl[64 * 6];
    int t = threadIdx.x;
    for (int i = t; i < 64 * 6; i += blockDim.x) Wl[i] = W3[i];
    __syncthreads();
    int n = blockIdx.x * blockDim.x + t;
    if (n >= N_NODES) return;
    float acc[6] = {0.f, 0.f, 0.f, 0.f, 0.f, 0.f};
    for (int k = 0; k < 64; ++k) {
        float xv = x[n * 64 + k];
#pragma unroll
        for (int c = 0; c < 6; ++c) acc[c] += xv * Wl[k * 6 + c];
    }
#pragma unroll
    for (int c = 0; c < 6; ++c) feat3[n * 6 + c] = acc[c];
#pragma unroll
    for (int h = 0; h < 3; ++h) {
        el3[n * 3 + h] = acc[h * 2 + 0] * al3[h * 2 + 0] + acc[h * 2 + 1] * al3[h * 2 + 1];
        er3[n * 3 + h] = acc[h * 2 + 0] * ar3[h * 2 + 0] + acc[h * 2 + 1] * ar3[h * 2 + 1];
    }
}

// ---------------- layer-3 aggregation: thread per node, writes f32 out ----------------
__global__ void k_agg3(const float* __restrict__ feat3, const float* __restrict__ el3,
                       const float* __restrict__ er3, const float* __restrict__ b3,
                       const int* __restrict__ rowp, const int* __restrict__ col,
                       float* __restrict__ out) {
    int n = blockIdx.x * blockDim.x + threadIdx.x;
    if (n >= N_NODES) return;
    int jb = rowp[n], je = rowp[n + 1];
    float er0 = er3[n * 3 + 0], er1 = er3[n * 3 + 1], er2 = er3[n * 3 + 2];
    float s0 = 0.f, s1 = 0.f, s2 = 0.f;
    float a[6] = {0.f, 0.f, 0.f, 0.f, 0.f, 0.f};
    for (int j = jb; j < je; ++j) {
        int s = col[j];
        float w0 = __expf(lrelu(el3[s * 3 + 0] + er0));
        float w1 = __expf(lrelu(el3[s * 3 + 1] + er1));
        float w2 = __expf(lrelu(el3[s * 3 + 2] + er2));
        const float* fs = feat3 + (long)s * 6;
        s0 += w0; s1 += w1; s2 += w2;
        a[0] += w0 * fs[0]; a[1] += w0 * fs[1];
        a[2] += w1 * fs[2]; a[3] += w1 * fs[3];
        a[4] += w2 * fs[4]; a[5] += w2 * fs[5];
    }
    float o0 = b3[0] + b3[2] + b3[4];
    float o1 = b3[1] + b3[3] + b3[5];
    if (je > jb) {
        o0 += a[0] / s0 + a[2] / s1 + a[4] / s2;
        o1 += a[1] / s0 + a[3] / s1 + a[5] / s2;
    }
    out[n * 2 + 0] = o0;
    out[n * 2 + 1] = o1;
}

extern "C" void kernel_launch(void* const* d_in, const int* in_sizes, int n_in,
                              void* d_out, int out_size, void* d_ws, size_t ws_size,
                              hipStream_t stream) {
    const float* feats = (const float*)d_in[0];
    const int* src = (const int*)d_in[1];
    const int* dst = (const int*)d_in[2];
    const float* W1 = (const float*)d_in[3];
    const float* al1 = (const float*)d_in[4];
    const float* ar1 = (const float*)d_in[5];
    const float* b1 = (const float*)d_in[6];
    const float* W2 = (const float*)d_in[7];
    const float* al2 = (const float*)d_in[8];
    const float* ar2 = (const float*)d_in[9];
    const float* b2 = (const float*)d_in[10];
    const float* W3 = (const float*)d_in[11];
    const float* al3 = (const float*)d_in[12];
    const float* ar3 = (const float*)d_in[13];
    const float* b3 = (const float*)d_in[14];
    float* out = (float*)d_out;

    // workspace layout (256B aligned)
    char* ws = (char*)d_ws;
    size_t off = 0;
    auto alloc = [&](size_t bytes) {
        void* p = ws + off;
        off += (bytes + 255) & ~(size_t)255;
        return p;
    };
    float* feat = (float*)alloc((size_t)N_NODES * 192 * 4);
    float* hbuf = (float*)alloc((size_t)N_NODES * 64 * 4);
    float* el = (float*)alloc((size_t)N_NODES * 3 * 4);
    float* er = (float*)alloc((size_t)N_NODES * 3 * 4);
    int* deg = (int*)alloc((size_t)N_NODES * 4);
    int* fill = (int*)alloc((size_t)N_NODES * 4);
    int* rowp = (int*)alloc((size_t)(N_NODES + 1) * 4);
    int* col = (int*)alloc((size_t)N_EDGES * 4);
    float* feat3 = (float*)alloc((size_t)N_NODES * 6 * 4);
    float* el3 = (float*)alloc((size_t)N_NODES * 3 * 4);
    float* er3 = (float*)alloc((size_t)N_NODES * 3 * 4);
    (void)ws_size;

    // ---- CSR build (deg and fill are adjacent -> one memset) ----
    hipMemsetAsync(deg, 0, 2 * (((size_t)N_NODES * 4 + 255) & ~(size_t)255), stream);
    int eb = (N_EDGES + 255) / 256;
    k_count<<<eb, 256, 0, stream>>>(dst, deg);
    k_scan<<<1, 1024, 0, stream>>>(deg, rowp);
    k_scatter<<<eb, 256, 0, stream>>>(src, dst, rowp, fill, col);

    int fb = (N_NODES + 7) / 8;            // k_feat blocks (NPB=8)
    int ab = (N_NODES + 3) / 4;            // k_agg blocks (4 waves/block)
    int nb = (N_NODES + 255) / 256;        // thread-per-node blocks

    // ---- layer 1: feats[N x 9] -> hbuf[N x 64] ----
    k_feat<9><<<fb, 192, 0, stream>>>(feats, W1, al1, ar1, feat, el, er);
    k_agg<<<ab, 256, 0, stream>>>(feat, el, er, b1, rowp, col, hbuf);

    // ---- layer 2: hbuf -> hbuf ----
    k_feat<64><<<fb, 192, 0, stream>>>(hbuf, W2, al2, ar2, feat, el, er);
    k_agg<<<ab, 256, 0, stream>>>(feat, el, er, b2, rowp, col, hbuf);

    // ---- layer 3: hbuf -> out[N x 2] ----
    k_feat3<<<nb, 256, 0, stream>>>(hbuf, W3, al3, ar3, feat3, el3, er3);
    k_agg3<<<nb, 256, 0, stream>>>(feat3, el3, er3, b3, rowp, col, out);
}

// Round 4
// 586.273 us; speedup vs baseline: 1.0273x; 1.0273x over previous
//
#include <hip/hip_runtime.h>
#include <hip/hip_fp16.h>

#define N_NODES 50000
#define N_EDGES 800000

static __device__ __forceinline__ float lrelu(float x) { return fmaxf(x, 0.2f * x); }

// ---------------- CSR build ----------------
__global__ void k_count(const int* __restrict__ dst, int* __restrict__ deg) {
    int e = blockIdx.x * blockDim.x + threadIdx.x;
    if (e < N_EDGES) atomicAdd(&deg[dst[e]], 1);
}

__global__ void k_scan(const int* __restrict__ deg, int* __restrict__ rowp) {
    __shared__ int part[1024];
    const int T = 1024;
    const int C = (N_NODES + T - 1) / T;  // 49
    int t = threadIdx.x;
    int lo = t * C;
    int hi = min(lo + C, N_NODES);
    int s = 0;
    for (int i = lo; i < hi; ++i) s += deg[i];
    part[t] = s;
    __syncthreads();
    for (int off = 1; off < T; off <<= 1) {
        int v = (t >= off) ? part[t - off] : 0;
        __syncthreads();
        part[t] += v;
        __syncthreads();
    }
    int base = (t == 0) ? 0 : part[t - 1];
    for (int i = lo; i < hi; ++i) { rowp[i] = base; base += deg[i]; }
    if (t == T - 1) rowp[N_NODES] = part[T - 1];
}

__global__ void k_scatter(const int* __restrict__ src, const int* __restrict__ dst,
                          const int* __restrict__ rowp, int* __restrict__ fill,
                          int* __restrict__ col) {
    int e = blockIdx.x * blockDim.x + threadIdx.x;
    if (e < N_EDGES) {
        int d = dst[e];
        int pos = rowp[d] + atomicAdd(&fill[d], 1);
        col[pos] = src[e];
    }
}

// ---------------- feat = x @ W (register-blocked), el/er, fp16 feat out -------
// block = 192 threads (3 waves; wave h == head h). GROUPS groups of 8 nodes.
// feat layout: half [N][192]  (node-major, 3 heads x 64 contiguous)
// el/er layout: float [N][4]  (padded for one float4 load in k_agg)
template <int K, int KP, int GROUPS>
__global__ void __launch_bounds__(192) k_feat(const float* __restrict__ x,
                                              const float* __restrict__ W,
                                              const float* __restrict__ al,
                                              const float* __restrict__ ar,
                                              __half* __restrict__ feat,
                                              float* __restrict__ el,
                                              float* __restrict__ er) {
    __shared__ float Wl[KP * 192];
    __shared__ float xl[8 * KP];
    const int c = threadIdx.x;  // output column = h*64+f
    const int h = c >> 6;
    // stage W once per block (pad rows K..KP-1 with zeros)
    for (int k = 0; k < KP; ++k) Wl[k * 192 + c] = (k < K) ? W[k * 192 + c] : 0.f;
    const float alc = al[c];
    const float arc = ar[c];

    for (int g = 0; g < GROUPS; ++g) {
        const int n0 = (blockIdx.x * GROUPS + g) * 8;  // grid sized exactly: no guard
        __syncthreads();  // protect xl from previous iteration's readers
        if (K == KP) {
            for (int idx = c; idx < 8 * K; idx += 192) xl[idx] = x[n0 * K + idx];
        } else {
            for (int idx = c; idx < 8 * KP; idx += 192) {
                int i = idx / KP, k = idx % KP;
                xl[idx] = (k < K) ? x[(n0 + i) * K + k] : 0.f;
            }
        }
        __syncthreads();

        float acc[8] = {0.f, 0.f, 0.f, 0.f, 0.f, 0.f, 0.f, 0.f};
#pragma unroll
        for (int k4 = 0; k4 < KP / 4; ++k4) {
            const float w0 = Wl[(4 * k4 + 0) * 192 + c];
            const float w1 = Wl[(4 * k4 + 1) * 192 + c];
            const float w2 = Wl[(4 * k4 + 2) * 192 + c];
            const float w3 = Wl[(4 * k4 + 3) * 192 + c];
#pragma unroll
            for (int i = 0; i < 8; ++i) {
                const float4 xv = *reinterpret_cast<const float4*>(&xl[i * KP + 4 * k4]);
                acc[i] += w0 * xv.x + w1 * xv.y + w2 * xv.z + w3 * xv.w;
            }
        }
#pragma unroll
        for (int i = 0; i < 8; ++i) {
            const float a = acc[i];
            feat[(size_t)(n0 + i) * 192 + c] = __float2half(a);
            float e1 = a * alc, e2 = a * arc;
#pragma unroll
            for (int off = 32; off > 0; off >>= 1) {
                e1 += __shfl_down(e1, off);
                e2 += __shfl_down(e2, off);
            }
            if ((c & 63) == 0) {
                el[(size_t)(n0 + i) * 4 + h] = e1;
                er[(size_t)(n0 + i) * 4 + h] = e2;
            }
        }
    }
}

// ---------------- aggregation: one wave per destination node (F=64) ----------
__global__ void __launch_bounds__(256) k_agg(const __half* __restrict__ feat,
                                             const float* __restrict__ el,
                                             const float* __restrict__ er,
                                             const float* __restrict__ bias,
                                             const int* __restrict__ rowp,
                                             const int* __restrict__ col,
                                             float* __restrict__ hout) {
    const int n = (blockIdx.x * blockDim.x + threadIdx.x) >> 6;
    const int lane = threadIdx.x & 63;
    if (n >= N_NODES) return;
    const int jb = rowp[n], je = rowp[n + 1];
    const float4 ern = *reinterpret_cast<const float4*>(er + (size_t)n * 4);
    float a0 = 0.f, a1 = 0.f, a2 = 0.f;
    float s0 = 0.f, s1 = 0.f, s2 = 0.f;

    int j = jb;
    for (; j + 1 < je; j += 2) {
        const int sA = __builtin_amdgcn_readfirstlane(col[j]);
        const int sB = __builtin_amdgcn_readfirstlane(col[j + 1]);
        const float4 eA = *reinterpret_cast<const float4*>(el + (size_t)sA * 4);
        const float4 eB = *reinterpret_cast<const float4*>(el + (size_t)sB * 4);
        const __half* pA = feat + (size_t)sA * 192;
        const __half* pB = feat + (size_t)sB * 192;
        const float fA0 = __half2float(pA[lane]);
        const float fA1 = __half2float(pA[64 + lane]);
        const float fA2 = __half2float(pA[128 + lane]);
        const float fB0 = __half2float(pB[lane]);
        const float fB1 = __half2float(pB[64 + lane]);
        const float fB2 = __half2float(pB[128 + lane]);
        const float wA0 = __expf(lrelu(eA.x + ern.x));
        const float wA1 = __expf(lrelu(eA.y + ern.y));
        const float wA2 = __expf(lrelu(eA.z + ern.z));
        const float wB0 = __expf(lrelu(eB.x + ern.x));
        const float wB1 = __expf(lrelu(eB.y + ern.y));
        const float wB2 = __expf(lrelu(eB.z + ern.z));
        a0 += wA0 * fA0 + wB0 * fB0;
        a1 += wA1 * fA1 + wB1 * fB1;
        a2 += wA2 * fA2 + wB2 * fB2;
        s0 += wA0 + wB0; s1 += wA1 + wB1; s2 += wA2 + wB2;
    }
    if (j < je) {
        const int s = __builtin_amdgcn_readfirstlane(col[j]);
        const float4 e4 = *reinterpret_cast<const float4*>(el + (size_t)s * 4);
        const __half* p = feat + (size_t)s * 192;
        const float w0 = __expf(lrelu(e4.x + ern.x));
        const float w1 = __expf(lrelu(e4.y + ern.y));
        const float w2 = __expf(lrelu(e4.z + ern.z));
        a0 += w0 * __half2float(p[lane]);
        a1 += w1 * __half2float(p[64 + lane]);
        a2 += w2 * __half2float(p[128 + lane]);
        s0 += w0; s1 += w1; s2 += w2;
    }
    float r = 0.f;
    if (je > jb) r = a0 / s0 + a1 / s1 + a2 / s2;
    r += bias[lane] + bias[64 + lane] + bias[128 + lane];
    hout[(size_t)n * 64 + lane] = r;
}

// ---------------- layer 3: feat3 = h @ W3 (64->6), el3/er3 -------------------
// block = 256 threads: 32 nodes/block, 8 thread-slots per node (6 used).
// feat3 layout: float [N][8] (padded); el3/er3: float [N][4].
__global__ void __launch_bounds__(256) k_feat3(const float* __restrict__ x,
                                               const float* __restrict__ W3,
                                               const float* __restrict__ al3,
                                               const float* __restrict__ ar3,
                                               float* __restrict__ feat3,
                                               float* __restrict__ el3,
                                               float* __restrict__ er3) {
    __shared__ float Wl[64 * 6];
    __shared__ float xl[32 * 64];
    __shared__ float fl[32 * 8];
    const int t = threadIdx.x;
    const int n0 = blockIdx.x * 32;
    const int nvalid = min(32, N_NODES - n0);
    for (int idx = t; idx < 384; idx += 256) Wl[idx] = W3[idx];  // R4 fix: strided (384 > blockDim)
    for (int idx = t; idx < nvalid * 64; idx += 256) xl[idx] = x[(size_t)n0 * 64 + idx];
    __syncthreads();

    const int i = t >> 3;      // node within block
    const int slot = t & 7;    // 0..5 = output col, 6..7 idle
    if (i < nvalid && slot < 6) {
        float acc = 0.f;
#pragma unroll
        for (int k4 = 0; k4 < 16; ++k4) {
            const float4 xv = *reinterpret_cast<const float4*>(&xl[i * 64 + 4 * k4]);
            acc += Wl[(4 * k4 + 0) * 6 + slot] * xv.x;
            acc += Wl[(4 * k4 + 1) * 6 + slot] * xv.y;
            acc += Wl[(4 * k4 + 2) * 6 + slot] * xv.z;
            acc += Wl[(4 * k4 + 3) * 6 + slot] * xv.w;
        }
        fl[i * 8 + slot] = acc;
        feat3[(size_t)(n0 + i) * 8 + slot] = acc;
    }
    __syncthreads();
    if (i < nvalid && slot < 6) {
        if (slot < 3) {
            const int h = slot;
            el3[(size_t)(n0 + i) * 4 + h] =
                fl[i * 8 + 2 * h] * al3[2 * h] + fl[i * 8 + 2 * h + 1] * al3[2 * h + 1];
        } else {
            const int h = slot - 3;
            er3[(size_t)(n0 + i) * 4 + h] =
                fl[i * 8 + 2 * h] * ar3[2 * h] + fl[i * 8 + 2 * h + 1] * ar3[2 * h + 1];
        }
    }
}

// ---------------- layer-3 aggregation: 8 lanes per node ----------------------
__global__ void __launch_bounds__(256) k_agg3(const float* __restrict__ feat3,
                                              const float* __restrict__ el3,
                                              const float* __restrict__ er3,
                                              const float* __restrict__ b3,
                                              const int* __restrict__ rowp,
                                              const int* __restrict__ col,
                                              float* __restrict__ out) {
    const int t = blockIdx.x * blockDim.x + threadIdx.x;
    const int n = t >> 3;
    const int r = t & 7;       // feature slot (0..5 valid; head = r/2)
    if (n >= N_NODES) return;
    int hh = r >> 1; if (hh > 2) hh = 2;
    const float ero = er3[(size_t)n * 4 + hh];
    const int jb = rowp[n], je = rowp[n + 1];
    float a = 0.f, sw = 0.f;
    for (int j = jb; j < je; ++j) {
        const int s = col[j];
        const float w = __expf(lrelu(el3[(size_t)s * 4 + hh] + ero));
        const float f = feat3[(size_t)s * 8 + r];   // r=6,7 read pad (discarded)
        a += w * f;
        sw += w;
    }
    float v = (je > jb && r < 6) ? (a / sw) : 0.f;
    v += __shfl_down(v, 2, 8);
    v += __shfl_down(v, 4, 8);   // lane0 = class0 sum over heads, lane1 = class1
    if (r < 2) {
        const float bc = b3[r] + b3[r + 2] + b3[r + 4];
        out[(size_t)n * 2 + r] = v + bc;
    }
}

extern "C" void kernel_launch(void* const* d_in, const int* in_sizes, int n_in,
                              void* d_out, int out_size, void* d_ws, size_t ws_size,
                              hipStream_t stream) {
    const float* feats = (const float*)d_in[0];
    const int* src = (const int*)d_in[1];
    const int* dst = (const int*)d_in[2];
    const float* W1 = (const float*)d_in[3];
    const float* al1 = (const float*)d_in[4];
    const float* ar1 = (const float*)d_in[5];
    const float* b1 = (const float*)d_in[6];
    const float* W2 = (const float*)d_in[7];
    const float* al2 = (const float*)d_in[8];
    const float* ar2 = (const float*)d_in[9];
    const float* b2 = (const float*)d_in[10];
    const float* W3 = (const float*)d_in[11];
    const float* al3 = (const float*)d_in[12];
    const float* ar3 = (const float*)d_in[13];
    const float* b3 = (const float*)d_in[14];
    float* out = (float*)d_out;

    char* ws = (char*)d_ws;
    size_t off = 0;
    auto alloc = [&](size_t bytes) {
        void* p = ws + off;
        off += (bytes + 255) & ~(size_t)255;
        return p;
    };
    __half* featH = (__half*)alloc((size_t)N_NODES * 192 * 2);  // 19.2 MB
    float* hbuf = (float*)alloc((size_t)N_NODES * 64 * 4);      // 12.8 MB
    float* el = (float*)alloc((size_t)N_NODES * 4 * 4);
    float* er = (float*)alloc((size_t)N_NODES * 4 * 4);
    int* deg = (int*)alloc((size_t)N_NODES * 4);
    int* fill = (int*)alloc((size_t)N_NODES * 4);
    int* rowp = (int*)alloc((size_t)(N_NODES + 1) * 4);
    int* col = (int*)alloc((size_t)N_EDGES * 4);
    float* feat3 = (float*)alloc((size_t)N_NODES * 8 * 4);
    float* el3 = (float*)alloc((size_t)N_NODES * 4 * 4);
    float* er3 = (float*)alloc((size_t)N_NODES * 4 * 4);
    (void)ws_size;

    // ---- CSR build (deg & fill adjacent -> one memset) ----
    hipMemsetAsync(deg, 0, 2 * (((size_t)N_NODES * 4 + 255) & ~(size_t)255), stream);
    int eb = (N_EDGES + 255) / 256;
    k_count<<<eb, 256, 0, stream>>>(dst, deg);
    k_scan<<<1, 1024, 0, stream>>>(deg, rowp);
    k_scatter<<<eb, 256, 0, stream>>>(src, dst, rowp, fill, col);

    const int fb = 1250;                    // 1250 blocks x 5 groups x 8 = 50000
    const int ab = (N_NODES + 3) / 4;       // k_agg: 4 waves/block
    const int nb3 = (N_NODES + 31) / 32;    // k_feat3 / k_agg3: 32 nodes/block

    // ---- layer 1 ----
    k_feat<9, 12, 5><<<fb, 192, 0, stream>>>(feats, W1, al1, ar1, featH, el, er);
    k_agg<<<ab, 256, 0, stream>>>(featH, el, er, b1, rowp, col, hbuf);

    // ---- layer 2 ----
    k_feat<64, 64, 5><<<fb, 192, 0, stream>>>(hbuf, W2, al2, ar2, featH, el, er);
    k_agg<<<ab, 256, 0, stream>>>(featH, el, er, b2, rowp, col, hbuf);

    // ---- layer 3 ----
    k_feat3<<<nb3, 256, 0, stream>>>(hbuf, W3, al3, ar3, feat3, el3, er3);
    k_agg3<<<nb3, 256, 0, stream>>>(feat3, el3, er3, b3, rowp, col, out);
}

// Round 5
// 477.893 us; speedup vs baseline: 1.2603x; 1.2268x over previous
//
#include <hip/hip_runtime.h>
#include <hip/hip_fp16.h>

#define N_NODES 50000
#define N_EDGES 800000

static __device__ __forceinline__ float lrelu(float x) { return fmaxf(x, 0.2f * x); }

// ---------------- CSR build ----------------
__global__ void k_count(const int* __restrict__ dst, int* __restrict__ deg) {
    int e = blockIdx.x * blockDim.x + threadIdx.x;
    if (e < N_EDGES) atomicAdd(&deg[dst[e]], 1);
}

__global__ void k_scan(const int* __restrict__ deg, int* __restrict__ rowp) {
    __shared__ int part[1024];
    const int T = 1024;
    const int C = (N_NODES + T - 1) / T;  // 49
    int t = threadIdx.x;
    int lo = t * C;
    int hi = min(lo + C, N_NODES);
    int s = 0;
    for (int i = lo; i < hi; ++i) s += deg[i];
    part[t] = s;
    __syncthreads();
    for (int off = 1; off < T; off <<= 1) {
        int v = (t >= off) ? part[t - off] : 0;
        __syncthreads();
        part[t] += v;
        __syncthreads();
    }
    int base = (t == 0) ? 0 : part[t - 1];
    for (int i = lo; i < hi; ++i) { rowp[i] = base; base += deg[i]; }
    if (t == T - 1) rowp[N_NODES] = part[T - 1];
}

__global__ void k_scatter(const int* __restrict__ src, const int* __restrict__ dst,
                          const int* __restrict__ rowp, int* __restrict__ fill,
                          int* __restrict__ col) {
    int e = blockIdx.x * blockDim.x + threadIdx.x;
    if (e < N_EDGES) {
        int d = dst[e];
        int pos = rowp[d] + atomicAdd(&fill[d], 1);
        col[pos] = src[e];
    }
}

// ---------------- feat = x @ W : W in VGPRs, x via wave-uniform loads ---------
// block = 192 threads (3 waves; wave h == head h). GROUPS groups of NPG nodes.
// No LDS. W column c lives in wreg[K]; x row is wave-uniform (scalar loads).
// feat layout: half [N][192]; el/er: float [N][4] (padded for float4 in k_agg).
template <int K, int NPG, int GROUPS>
__global__ void __launch_bounds__(192) k_feat(const float* __restrict__ x,
                                              const float* __restrict__ W,
                                              const float* __restrict__ al,
                                              const float* __restrict__ ar,
                                              __half* __restrict__ feat,
                                              float* __restrict__ el,
                                              float* __restrict__ er) {
    const int c = threadIdx.x;  // output column = h*64+f
    const int h = c >> 6;
    float wreg[K];
#pragma unroll
    for (int k = 0; k < K; ++k) wreg[k] = W[k * 192 + c];
    const float alc = al[c];
    const float arc = ar[c];

    for (int g = 0; g < GROUPS; ++g) {
        const int nbase = (blockIdx.x * GROUPS + g) * NPG;  // grid sized exactly
        float acc[NPG];
#pragma unroll
        for (int i = 0; i < NPG; ++i) acc[i] = 0.f;
#pragma unroll
        for (int i = 0; i < NPG; ++i) {
            // pin node index scalar so x-row loads are provably wave-uniform
            const int n = __builtin_amdgcn_readfirstlane(nbase + i);
            const float* __restrict__ xr = x + (size_t)n * K;
#pragma unroll
            for (int k = 0; k < K; ++k) acc[i] += xr[k] * wreg[k];
        }
#pragma unroll
        for (int i = 0; i < NPG; ++i) {
            const float a = acc[i];
            feat[(size_t)(nbase + i) * 192 + c] = __float2half(a);
            float e1 = a * alc, e2 = a * arc;
#pragma unroll
            for (int off = 32; off > 0; off >>= 1) {
                e1 += __shfl_down(e1, off);
                e2 += __shfl_down(e2, off);
            }
            if ((c & 63) == 0) {
                el[(size_t)(nbase + i) * 4 + h] = e1;
                er[(size_t)(nbase + i) * 4 + h] = e2;
            }
        }
    }
}

// ---------------- aggregation: one wave per destination node (F=64) ----------
__global__ void __launch_bounds__(256) k_agg(const __half* __restrict__ feat,
                                             const float* __restrict__ el,
                                             const float* __restrict__ er,
                                             const float* __restrict__ bias,
                                             const int* __restrict__ rowp,
                                             const int* __restrict__ col,
                                             float* __restrict__ hout) {
    const int n = (blockIdx.x * blockDim.x + threadIdx.x) >> 6;
    const int lane = threadIdx.x & 63;
    if (n >= N_NODES) return;
    const int jb = rowp[n], je = rowp[n + 1];
    const float4 ern = *reinterpret_cast<const float4*>(er + (size_t)n * 4);
    float a0 = 0.f, a1 = 0.f, a2 = 0.f;
    float s0 = 0.f, s1 = 0.f, s2 = 0.f;

    int j = jb;
    for (; j + 1 < je; j += 2) {
        const int sA = __builtin_amdgcn_readfirstlane(col[j]);
        const int sB = __builtin_amdgcn_readfirstlane(col[j + 1]);
        const float4 eA = *reinterpret_cast<const float4*>(el + (size_t)sA * 4);
        const float4 eB = *reinterpret_cast<const float4*>(el + (size_t)sB * 4);
        const __half* pA = feat + (size_t)sA * 192;
        const __half* pB = feat + (size_t)sB * 192;
        const float fA0 = __half2float(pA[lane]);
        const float fA1 = __half2float(pA[64 + lane]);
        const float fA2 = __half2float(pA[128 + lane]);
        const float fB0 = __half2float(pB[lane]);
        const float fB1 = __half2float(pB[64 + lane]);
        const float fB2 = __half2float(pB[128 + lane]);
        const float wA0 = __expf(lrelu(eA.x + ern.x));
        const float wA1 = __expf(lrelu(eA.y + ern.y));
        const float wA2 = __expf(lrelu(eA.z + ern.z));
        const float wB0 = __expf(lrelu(eB.x + ern.x));
        const float wB1 = __expf(lrelu(eB.y + ern.y));
        const float wB2 = __expf(lrelu(eB.z + ern.z));
        a0 += wA0 * fA0 + wB0 * fB0;
        a1 += wA1 * fA1 + wB1 * fB1;
        a2 += wA2 * fA2 + wB2 * fB2;
        s0 += wA0 + wB0; s1 += wA1 + wB1; s2 += wA2 + wB2;
    }
    if (j < je) {
        const int s = __builtin_amdgcn_readfirstlane(col[j]);
        const float4 e4 = *reinterpret_cast<const float4*>(el + (size_t)s * 4);
        const __half* p = feat + (size_t)s * 192;
        const float w0 = __expf(lrelu(e4.x + ern.x));
        const float w1 = __expf(lrelu(e4.y + ern.y));
        const float w2 = __expf(lrelu(e4.z + ern.z));
        a0 += w0 * __half2float(p[lane]);
        a1 += w1 * __half2float(p[64 + lane]);
        a2 += w2 * __half2float(p[128 + lane]);
        s0 += w0; s1 += w1; s2 += w2;
    }
    float r = 0.f;
    if (je > jb) r = a0 / s0 + a1 / s1 + a2 / s2;
    r += bias[lane] + bias[64 + lane] + bias[128 + lane];
    hout[(size_t)n * 64 + lane] = r;
}

// ---------------- layer 3: feat3 = h @ W3 (64->6), el3/er3 -------------------
// block = 256 threads: 32 nodes/block, 8 thread-slots per node (6 used).
// feat3 layout: float [N][8] (padded); el3/er3: float [N][4].
__global__ void __launch_bounds__(256) k_feat3(const float* __restrict__ x,
                                               const float* __restrict__ W3,
                                               const float* __restrict__ al3,
                                               const float* __restrict__ ar3,
                                               float* __restrict__ feat3,
                                               float* __restrict__ el3,
                                               float* __restrict__ er3) {
    __shared__ float Wl[64 * 6];
    __shared__ float xl[32 * 64];
    __shared__ float fl[32 * 8];
    const int t = threadIdx.x;
    const int n0 = blockIdx.x * 32;
    const int nvalid = min(32, N_NODES - n0);
    for (int idx = t; idx < 384; idx += 256) Wl[idx] = W3[idx];  // strided (384 > blockDim)
    for (int idx = t; idx < nvalid * 64; idx += 256) xl[idx] = x[(size_t)n0 * 64 + idx];
    __syncthreads();

    const int i = t >> 3;      // node within block
    const int slot = t & 7;    // 0..5 = output col, 6..7 idle
    if (i < nvalid && slot < 6) {
        float acc = 0.f;
#pragma unroll
        for (int k4 = 0; k4 < 16; ++k4) {
            const float4 xv = *reinterpret_cast<const float4*>(&xl[i * 64 + 4 * k4]);
            acc += Wl[(4 * k4 + 0) * 6 + slot] * xv.x;
            acc += Wl[(4 * k4 + 1) * 6 + slot] * xv.y;
            acc += Wl[(4 * k4 + 2) * 6 + slot] * xv.z;
            acc += Wl[(4 * k4 + 3) * 6 + slot] * xv.w;
        }
        fl[i * 8 + slot] = acc;
        feat3[(size_t)(n0 + i) * 8 + slot] = acc;
    }
    __syncthreads();
    if (i < nvalid && slot < 6) {
        if (slot < 3) {
            const int h = slot;
            el3[(size_t)(n0 + i) * 4 + h] =
                fl[i * 8 + 2 * h] * al3[2 * h] + fl[i * 8 + 2 * h + 1] * al3[2 * h + 1];
        } else {
            const int h = slot - 3;
            er3[(size_t)(n0 + i) * 4 + h] =
                fl[i * 8 + 2 * h] * ar3[2 * h] + fl[i * 8 + 2 * h + 1] * ar3[2 * h + 1];
        }
    }
}

// ---------------- layer-3 aggregation: 8 lanes per node ----------------------
__global__ void __launch_bounds__(256) k_agg3(const float* __restrict__ feat3,
                                              const float* __restrict__ el3,
                                              const float* __restrict__ er3,
                                              const float* __restrict__ b3,
                                              const int* __restrict__ rowp,
                                              const int* __restrict__ col,
                                              float* __restrict__ out) {
    const int t = blockIdx.x * blockDim.x + threadIdx.x;
    const int n = t >> 3;
    const int r = t & 7;       // feature slot (0..5 valid; head = r/2)
    if (n >= N_NODES) return;
    int hh = r >> 1; if (hh > 2) hh = 2;
    const float ero = er3[(size_t)n * 4 + hh];
    const int jb = rowp[n], je = rowp[n + 1];
    float a = 0.f, sw = 0.f;
    for (int j = jb; j < je; ++j) {
        const int s = col[j];
        const float w = __expf(lrelu(el3[(size_t)s * 4 + hh] + ero));
        const float f = feat3[(size_t)s * 8 + r];   // r=6,7 read pad (discarded)
        a += w * f;
        sw += w;
    }
    float v = (je > jb && r < 6) ? (a / sw) : 0.f;
    v += __shfl_down(v, 2, 8);
    v += __shfl_down(v, 4, 8);   // lane0 = class0 sum over heads, lane1 = class1
    if (r < 2) {
        const float bc = b3[r] + b3[r + 2] + b3[r + 4];
        out[(size_t)n * 2 + r] = v + bc;
    }
}

extern "C" void kernel_launch(void* const* d_in, const int* in_sizes, int n_in,
                              void* d_out, int out_size, void* d_ws, size_t ws_size,
                              hipStream_t stream) {
    const float* feats = (const float*)d_in[0];
    const int* src = (const int*)d_in[1];
    const int* dst = (const int*)d_in[2];
    const float* W1 = (const float*)d_in[3];
    const float* al1 = (const float*)d_in[4];
    const float* ar1 = (const float*)d_in[5];
    const float* b1 = (const float*)d_in[6];
    const float* W2 = (const float*)d_in[7];
    const float* al2 = (const float*)d_in[8];
    const float* ar2 = (const float*)d_in[9];
    const float* b2 = (const float*)d_in[10];
    const float* W3 = (const float*)d_in[11];
    const float* al3 = (const float*)d_in[12];
    const float* ar3 = (const float*)d_in[13];
    const float* b3 = (const float*)d_in[14];
    float* out = (float*)d_out;

    char* ws = (char*)d_ws;
    size_t off = 0;
    auto alloc = [&](size_t bytes) {
        void* p = ws + off;
        off += (bytes + 255) & ~(size_t)255;
        return p;
    };
    __half* featH = (__half*)alloc((size_t)N_NODES * 192 * 2);  // 19.2 MB
    float* hbuf = (float*)alloc((size_t)N_NODES * 64 * 4);      // 12.8 MB
    float* el = (float*)alloc((size_t)N_NODES * 4 * 4);
    float* er = (float*)alloc((size_t)N_NODES * 4 * 4);
    int* deg = (int*)alloc((size_t)N_NODES * 4);
    int* fill = (int*)alloc((size_t)N_NODES * 4);
    int* rowp = (int*)alloc((size_t)(N_NODES + 1) * 4);
    int* col = (int*)alloc((size_t)N_EDGES * 4);
    float* feat3 = (float*)alloc((size_t)N_NODES * 8 * 4);
    float* el3 = (float*)alloc((size_t)N_NODES * 4 * 4);
    float* er3 = (float*)alloc((size_t)N_NODES * 4 * 4);
    (void)ws_size;

    // ---- CSR build (deg & fill adjacent -> one memset) ----
    hipMemsetAsync(deg, 0, 2 * (((size_t)N_NODES * 4 + 255) & ~(size_t)255), stream);
    int eb = (N_EDGES + 255) / 256;
    k_count<<<eb, 256, 0, stream>>>(dst, deg);
    k_scan<<<1, 1024, 0, stream>>>(deg, rowp);
    k_scatter<<<eb, 256, 0, stream>>>(src, dst, rowp, fill, col);

    const int fb = 2500;                    // 2500 blocks x 5 groups x 4 = 50000
    const int ab = (N_NODES + 3) / 4;       // k_agg: 4 waves/block
    const int nb3 = (N_NODES + 31) / 32;    // k_feat3 / k_agg3: 32 nodes/block

    // ---- layer 1 ----
    k_feat<9, 4, 5><<<fb, 192, 0, stream>>>(feats, W1, al1, ar1, featH, el, er);
    k_agg<<<ab, 256, 0, stream>>>(featH, el, er, b1, rowp, col, hbuf);

    // ---- layer 2 ----
    k_feat<64, 4, 5><<<fb, 192, 0, stream>>>(hbuf, W2, al2, ar2, featH, el, er);
    k_agg<<<ab, 256, 0, stream>>>(featH, el, er, b2, rowp, col, hbuf);

    // ---- layer 3 ----
    k_feat3<<<nb3, 256, 0, stream>>>(hbuf, W3, al3, ar3, feat3, el3, er3);
    k_agg3<<<nb3, 256, 0, stream>>>(feat3, el3, er3, b3, rowp, col, out);
}

// Round 6
// 406.587 us; speedup vs baseline: 1.4813x; 1.1754x over previous
//
#include <hip/hip_runtime.h>
#include <hip/hip_fp16.h>

#define N_NODES 50000
#define N_EDGES 800000
#define NB_SCAN 49          // ceil(50000 / 1024)
#define DEG_PAD (NB_SCAN * 1024)   // 50176, zero-padded so int4 loads are unguarded

static __device__ __forceinline__ float lrelu(float x) { return fmaxf(x, 0.2f * x); }

// ---------------- CSR build ----------------
__global__ void k_count(const int* __restrict__ dst, int* __restrict__ deg) {
    int e = blockIdx.x * blockDim.x + threadIdx.x;
    if (e < N_EDGES) atomicAdd(&deg[dst[e]], 1);
}

// Phase A: per-block (1024 elems) sums
__global__ void __launch_bounds__(256) k_scanA(const int* __restrict__ deg,
                                               int* __restrict__ bsum) {
    const int t = threadIdx.x;
    const int b = blockIdx.x;
    const int base = (b * 256 + t) * 4;
    const int4 v = *reinterpret_cast<const int4*>(deg + base);  // padded: safe
    int s = v.x + v.y + v.z + v.w;
#pragma unroll
    for (int off = 32; off > 0; off >>= 1) s += __shfl_down(s, off);
    __shared__ int ws[4];
    if ((t & 63) == 0) ws[t >> 6] = s;
    __syncthreads();
    if (t == 0) bsum[b] = ws[0] + ws[1] + ws[2] + ws[3];
}

// Phase B: exclusive scan of 49 block sums (single wave)
__global__ void __launch_bounds__(64) k_scanB(const int* __restrict__ bsum,
                                              int* __restrict__ boff,
                                              int* __restrict__ rowp) {
    const int t = threadIdx.x;
    const int v = (t < NB_SCAN) ? bsum[t] : 0;
    int inc = v;
#pragma unroll
    for (int off = 1; off < 64; off <<= 1) {
        const int u = __shfl_up(inc, off);
        if (t >= off) inc += u;
    }
    if (t < NB_SCAN) boff[t] = inc - v;
    if (t == 0) rowp[N_NODES] = N_EDGES;  // total degree == E (all dst in range)
}

// Phase C: block-local scan + block offset -> rowp
__global__ void __launch_bounds__(256) k_scanC(const int* __restrict__ deg,
                                               const int* __restrict__ boff,
                                               int* __restrict__ rowp) {
    const int t = threadIdx.x;
    const int b = blockIdx.x;
    const int lane = t & 63;
    const int wv = t >> 6;
    const int base = (b * 256 + t) * 4;
    const int4 v = *reinterpret_cast<const int4*>(deg + base);
    const int s = v.x + v.y + v.z + v.w;
    int inc = s;
#pragma unroll
    for (int off = 1; off < 64; off <<= 1) {
        const int u = __shfl_up(inc, off);
        if (lane >= off) inc += u;
    }
    __shared__ int wsum[4];
    if (lane == 63) wsum[wv] = inc;
    __syncthreads();
    int add = boff[b];
    for (int w = 0; w < wv; ++w) add += wsum[w];
    const int exc = add + inc - s;  // exclusive prefix at this thread's first elem
    if (base < N_NODES) rowp[base] = exc;
    if (base + 1 < N_NODES) rowp[base + 1] = exc + v.x;
    if (base + 2 < N_NODES) rowp[base + 2] = exc + v.x + v.y;
    if (base + 3 < N_NODES) rowp[base + 3] = exc + v.x + v.y + v.z;
}

__global__ void k_scatter(const int* __restrict__ src, const int* __restrict__ dst,
                          const int* __restrict__ rowp, int* __restrict__ fill,
                          int* __restrict__ col) {
    int e = blockIdx.x * blockDim.x + threadIdx.x;
    if (e < N_EDGES) {
        int d = dst[e];
        int pos = rowp[d] + atomicAdd(&fill[d], 1);
        col[pos] = src[e];
    }
}

// ---------------- feat = x @ W : W in VGPRs, x via wave-uniform loads ---------
// block = 192 threads (3 waves; wave h == head h). GROUPS groups of NPG nodes.
// No LDS. W column c lives in wreg[K]; x row is wave-uniform (scalar loads).
// feat layout: half [N][192]; el/er: float [N][4] (padded for float4 in k_agg).
template <int K, int NPG, int GROUPS>
__global__ void __launch_bounds__(192) k_feat(const float* __restrict__ x,
                                              const float* __restrict__ W,
                                              const float* __restrict__ al,
                                              const float* __restrict__ ar,
                                              __half* __restrict__ feat,
                                              float* __restrict__ el,
                                              float* __restrict__ er) {
    const int c = threadIdx.x;  // output column = h*64+f
    const int h = c >> 6;
    float wreg[K];
#pragma unroll
    for (int k = 0; k < K; ++k) wreg[k] = W[k * 192 + c];
    const float alc = al[c];
    const float arc = ar[c];

    for (int g = 0; g < GROUPS; ++g) {
        const int nbase = (blockIdx.x * GROUPS + g) * NPG;  // grid sized exactly
        float acc[NPG];
#pragma unroll
        for (int i = 0; i < NPG; ++i) acc[i] = 0.f;
#pragma unroll
        for (int i = 0; i < NPG; ++i) {
            const int n = __builtin_amdgcn_readfirstlane(nbase + i);
            const float* __restrict__ xr = x + (size_t)n * K;
#pragma unroll
            for (int k = 0; k < K; ++k) acc[i] += xr[k] * wreg[k];
        }
#pragma unroll
        for (int i = 0; i < NPG; ++i) {
            const float a = acc[i];
            feat[(size_t)(nbase + i) * 192 + c] = __float2half(a);
            float e1 = a * alc, e2 = a * arc;
#pragma unroll
            for (int off = 32; off > 0; off >>= 1) {
                e1 += __shfl_down(e1, off);
                e2 += __shfl_down(e2, off);
            }
            if ((c & 63) == 0) {
                el[(size_t)(nbase + i) * 4 + h] = e1;
                er[(size_t)(nbase + i) * 4 + h] = e2;
            }
        }
    }
}

// ---------------- aggregation: one wave per destination node (F=64) ----------
__global__ void __launch_bounds__(256) k_agg(const __half* __restrict__ feat,
                                             const float* __restrict__ el,
                                             const float* __restrict__ er,
                                             const float* __restrict__ bias,
                                             const int* __restrict__ rowp,
                                             const int* __restrict__ col,
                                             float* __restrict__ hout) {
    const int n = (blockIdx.x * blockDim.x + threadIdx.x) >> 6;
    const int lane = threadIdx.x & 63;
    if (n >= N_NODES) return;
    const int jb = rowp[n], je = rowp[n + 1];
    const float4 ern = *reinterpret_cast<const float4*>(er + (size_t)n * 4);
    float a0 = 0.f, a1 = 0.f, a2 = 0.f;
    float s0 = 0.f, s1 = 0.f, s2 = 0.f;

    int j = jb;
    for (; j + 1 < je; j += 2) {
        const int sA = __builtin_amdgcn_readfirstlane(col[j]);
        const int sB = __builtin_amdgcn_readfirstlane(col[j + 1]);
        const float4 eA = *reinterpret_cast<const float4*>(el + (size_t)sA * 4);
        const float4 eB = *reinterpret_cast<const float4*>(el + (size_t)sB * 4);
        const __half* pA = feat + (size_t)sA * 192;
        const __half* pB = feat + (size_t)sB * 192;
        const float fA0 = __half2float(pA[lane]);
        const float fA1 = __half2float(pA[64 + lane]);
        const float fA2 = __half2float(pA[128 + lane]);
        const float fB0 = __half2float(pB[lane]);
        const float fB1 = __half2float(pB[64 + lane]);
        const float fB2 = __half2float(pB[128 + lane]);
        const float wA0 = __expf(lrelu(eA.x + ern.x));
        const float wA1 = __expf(lrelu(eA.y + ern.y));
        const float wA2 = __expf(lrelu(eA.z + ern.z));
        const float wB0 = __expf(lrelu(eB.x + ern.x));
        const float wB1 = __expf(lrelu(eB.y + ern.y));
        const float wB2 = __expf(lrelu(eB.z + ern.z));
        a0 += wA0 * fA0 + wB0 * fB0;
        a1 += wA1 * fA1 + wB1 * fB1;
        a2 += wA2 * fA2 + wB2 * fB2;
        s0 += wA0 + wB0; s1 += wA1 + wB1; s2 += wA2 + wB2;
    }
    if (j < je) {
        const int s = __builtin_amdgcn_readfirstlane(col[j]);
        const float4 e4 = *reinterpret_cast<const float4*>(el + (size_t)s * 4);
        const __half* p = feat + (size_t)s * 192;
        const float w0 = __expf(lrelu(e4.x + ern.x));
        const float w1 = __expf(lrelu(e4.y + ern.y));
        const float w2 = __expf(lrelu(e4.z + ern.z));
        a0 += w0 * __half2float(p[lane]);
        a1 += w1 * __half2float(p[64 + lane]);
        a2 += w2 * __half2float(p[128 + lane]);
        s0 += w0; s1 += w1; s2 += w2;
    }
    float r = 0.f;
    if (je > jb) r = a0 / s0 + a1 / s1 + a2 / s2;
    r += bias[lane] + bias[64 + lane] + bias[128 + lane];
    hout[(size_t)n * 64 + lane] = r;
}

// ---------------- layer 3: feat3 = h @ W3 (64->6), el3/er3 -------------------
__global__ void __launch_bounds__(256) k_feat3(const float* __restrict__ x,
                                               const float* __restrict__ W3,
                                               const float* __restrict__ al3,
                                               const float* __restrict__ ar3,
                                               float* __restrict__ feat3,
                                               float* __restrict__ el3,
                                               float* __restrict__ er3) {
    __shared__ float Wl[64 * 6];
    __shared__ float xl[32 * 64];
    __shared__ float fl[32 * 8];
    const int t = threadIdx.x;
    const int n0 = blockIdx.x * 32;
    const int nvalid = min(32, N_NODES - n0);
    for (int idx = t; idx < 384; idx += 256) Wl[idx] = W3[idx];
    for (int idx = t; idx < nvalid * 64; idx += 256) xl[idx] = x[(size_t)n0 * 64 + idx];
    __syncthreads();

    const int i = t >> 3;      // node within block
    const int slot = t & 7;    // 0..5 = output col, 6..7 idle
    if (i < nvalid && slot < 6) {
        float acc = 0.f;
#pragma unroll
        for (int k4 = 0; k4 < 16; ++k4) {
            const float4 xv = *reinterpret_cast<const float4*>(&xl[i * 64 + 4 * k4]);
            acc += Wl[(4 * k4 + 0) * 6 + slot] * xv.x;
            acc += Wl[(4 * k4 + 1) * 6 + slot] * xv.y;
            acc += Wl[(4 * k4 + 2) * 6 + slot] * xv.z;
            acc += Wl[(4 * k4 + 3) * 6 + slot] * xv.w;
        }
        fl[i * 8 + slot] = acc;
        feat3[(size_t)(n0 + i) * 8 + slot] = acc;
    }
    __syncthreads();
    if (i < nvalid && slot < 6) {
        if (slot < 3) {
            const int h = slot;
            el3[(size_t)(n0 + i) * 4 + h] =
                fl[i * 8 + 2 * h] * al3[2 * h] + fl[i * 8 + 2 * h + 1] * al3[2 * h + 1];
        } else {
            const int h = slot - 3;
            er3[(size_t)(n0 + i) * 4 + h] =
                fl[i * 8 + 2 * h] * ar3[2 * h] + fl[i * 8 + 2 * h + 1] * ar3[2 * h + 1];
        }
    }
}

// ---------------- layer-3 aggregation: 8 lanes per node ----------------------
__global__ void __launch_bounds__(256) k_agg3(const float* __restrict__ feat3,
                                              const float* __restrict__ el3,
                                              const float* __restrict__ er3,
                                              const float* __restrict__ b3,
                                              const int* __restrict__ rowp,
                                              const int* __restrict__ col,
                                              float* __restrict__ out) {
    const int t = blockIdx.x * blockDim.x + threadIdx.x;
    const int n = t >> 3;
    const int r = t & 7;       // feature slot (0..5 valid; head = r/2)
    if (n >= N_NODES) return;
    int hh = r >> 1; if (hh > 2) hh = 2;
    const float ero = er3[(size_t)n * 4 + hh];
    const int jb = rowp[n], je = rowp[n + 1];
    float a = 0.f, sw = 0.f;
    for (int j = jb; j < je; ++j) {
        const int s = col[j];
        const float w = __expf(lrelu(el3[(size_t)s * 4 + hh] + ero));
        const float f = feat3[(size_t)s * 8 + r];
        a += w * f;
        sw += w;
    }
    float v = (je > jb && r < 6) ? (a / sw) : 0.f;
    v += __shfl_down(v, 2, 8);
    v += __shfl_down(v, 4, 8);
    if (r < 2) {
        const float bc = b3[r] + b3[r + 2] + b3[r + 4];
        out[(size_t)n * 2 + r] = v + bc;
    }
}

extern "C" void kernel_launch(void* const* d_in, const int* in_sizes, int n_in,
                              void* d_out, int out_size, void* d_ws, size_t ws_size,
                              hipStream_t stream) {
    const float* feats = (const float*)d_in[0];
    const int* src = (const int*)d_in[1];
    const int* dst = (const int*)d_in[2];
    const float* W1 = (const float*)d_in[3];
    const float* al1 = (const float*)d_in[4];
    const float* ar1 = (const float*)d_in[5];
    const float* b1 = (const float*)d_in[6];
    const float* W2 = (const float*)d_in[7];
    const float* al2 = (const float*)d_in[8];
    const float* ar2 = (const float*)d_in[9];
    const float* b2 = (const float*)d_in[10];
    const float* W3 = (const float*)d_in[11];
    const float* al3 = (const float*)d_in[12];
    const float* ar3 = (const float*)d_in[13];
    const float* b3 = (const float*)d_in[14];
    float* out = (float*)d_out;

    char* ws = (char*)d_ws;
    size_t off = 0;
    auto alloc = [&](size_t bytes) {
        void* p = ws + off;
        off += (bytes + 255) & ~(size_t)255;
        return p;
    };
    __half* featH = (__half*)alloc((size_t)N_NODES * 192 * 2);  // 19.2 MB
    float* hbuf = (float*)alloc((size_t)N_NODES * 64 * 4);      // 12.8 MB
    float* el = (float*)alloc((size_t)N_NODES * 4 * 4);
    float* er = (float*)alloc((size_t)N_NODES * 4 * 4);
    int* deg = (int*)alloc((size_t)DEG_PAD * 4);                // zero-padded to 50176
    int* fill = (int*)alloc((size_t)DEG_PAD * 4);
    int* rowp = (int*)alloc((size_t)(N_NODES + 1) * 4);
    int* col = (int*)alloc((size_t)N_EDGES * 4);
    int* bsum = (int*)alloc(64 * 4);
    int* boff = (int*)alloc(64 * 4);
    float* feat3 = (float*)alloc((size_t)N_NODES * 8 * 4);
    float* el3 = (float*)alloc((size_t)N_NODES * 4 * 4);
    float* er3 = (float*)alloc((size_t)N_NODES * 4 * 4);
    (void)ws_size;

    // ---- CSR build (deg & fill adjacent -> one memset covers both + pads) ----
    hipMemsetAsync(deg, 0, 2 * (size_t)DEG_PAD * 4, stream);
    int eb = (N_EDGES + 255) / 256;
    k_count<<<eb, 256, 0, stream>>>(dst, deg);
    k_scanA<<<NB_SCAN, 256, 0, stream>>>(deg, bsum);
    k_scanB<<<1, 64, 0, stream>>>(bsum, boff, rowp);
    k_scanC<<<NB_SCAN, 256, 0, stream>>>(deg, boff, rowp);
    k_scatter<<<eb, 256, 0, stream>>>(src, dst, rowp, fill, col);

    const int fb = 2500;                    // 2500 blocks x 5 groups x 4 = 50000
    const int ab = (N_NODES + 3) / 4;       // k_agg: 4 waves/block
    const int nb3 = (N_NODES + 31) / 32;    // k_feat3 / k_agg3: 32 nodes/block

    // ---- layer 1 ----
    k_feat<9, 4, 5><<<fb, 192, 0, stream>>>(feats, W1, al1, ar1, featH, el, er);
    k_agg<<<ab, 256, 0, stream>>>(featH, el, er, b1, rowp, col, hbuf);

    // ---- layer 2 ----
    k_feat<64, 4, 5><<<fb, 192, 0, stream>>>(hbuf, W2, al2, ar2, featH, el, er);
    k_agg<<<ab, 256, 0, stream>>>(featH, el, er, b2, rowp, col, hbuf);

    // ---- layer 3 ----
    k_feat3<<<nb3, 256, 0, stream>>>(hbuf, W3, al3, ar3, feat3, el3, er3);
    k_agg3<<<nb3, 256, 0, stream>>>(feat3, el3, er3, b3, rowp, col, out);
}